// Round 6
// baseline (229.621 us; speedup 1.0000x reference)
//
#include <hip/hip_runtime.h>

// ArcFace loss, MI355X. B=512, D=512, C=64000, s=64, m=0.5.
// R6: wave tile 64x128 (acc 4x8) so each block covers 128 classes with
// A read ONCE per block -> K-loop L2 traffic halves to 256 MB (R5
// validated L2 request rate as the governor). sW = 128 KB (1 block/CU),
// no K-loop barriers, register prefetch of next-k A-frags.

#define B_N 512
#define D_N 512
#define C_N 64000
#define S_SCALE 64.0f
#define MARGIN 0.5f
#define EPS_C 1e-7f
#define NREP 16

typedef unsigned short ushort_t;
typedef __attribute__((ext_vector_type(8))) short short8;   // 8 bf16 (4 VGPRs)
typedef __attribute__((ext_vector_type(4))) float floatx4;  // MFMA acc

__device__ __forceinline__ ushort_t f2bf(float f) {
    unsigned int u = __float_as_uint(f);
    u += 0x7fffu + ((u >> 16) & 1u);  // round-to-nearest-even
    return (ushort_t)(u >> 16);
}

// Normalize x rows -> bf16 in fragment-linear layout:
//   xnT element addr = (kc*512 + row)*8 + j,  kc = k/8 in [0,64), j = k%8.
// Blocks 0..127: 4 rows each. Block 128: zero rowsum replicas.
__global__ void xprep_kernel(const float* __restrict__ x,
                             ushort_t* __restrict__ xnT,
                             float* __restrict__ rowsumR) {
    int b = blockIdx.x;
    int t = threadIdx.x;
    if (b == 128) {
#pragma unroll
        for (int i = 0; i < NREP * B_N / 256; ++i)
            rowsumR[i * 256 + t] = 0.0f;
        return;
    }
    int row  = b * 4 + (t >> 6);
    int lane = t & 63;
    const float4* p = (const float4*)(x + (size_t)row * D_N);
    float4 v0 = p[lane * 2];        // elems [lane*8 .. lane*8+3]
    float4 v1 = p[lane * 2 + 1];    // elems [lane*8+4 .. lane*8+7]
    float ss = v0.x*v0.x + v0.y*v0.y + v0.z*v0.z + v0.w*v0.w
             + v1.x*v1.x + v1.y*v1.y + v1.z*v1.z + v1.w*v1.w;
#pragma unroll
    for (int off = 32; off > 0; off >>= 1) ss += __shfl_xor(ss, off);
    float sc = 1.0f / fmaxf(sqrtf(ss), 1e-12f);
    uint4 o;
    o.x = (unsigned)f2bf(v0.x*sc) | ((unsigned)f2bf(v0.y*sc) << 16);
    o.y = (unsigned)f2bf(v0.z*sc) | ((unsigned)f2bf(v0.w*sc) << 16);
    o.z = (unsigned)f2bf(v1.x*sc) | ((unsigned)f2bf(v1.y*sc) << 16);
    o.w = (unsigned)f2bf(v1.z*sc) | ((unsigned)f2bf(v1.w*sc) << 16);
    *((uint4*)(xnT + ((size_t)(lane << 9) + row) * 8)) = o;
}

// One block = 128 classes x 512 rows. 8 waves; wave w owns rows
// [w*64, w*64+64) x ALL 128 cols (4x8 mfma_f32_16x16x32_bf16 frags).
// sW: addr = kc*1024 + (col^(kc&7))*8 + j (XOR swizzle, 0-conflict
// verified pattern from R4/R5). A-frags from fragment-linear xnT in L2.
__global__ __launch_bounds__(512, 2)
void gemm_fused_kernel(const float* __restrict__ W,
                       const ushort_t* __restrict__ xnT,
                       const int* __restrict__ y,
                       float* __restrict__ rowsumR,
                       float* __restrict__ tgt) {
    __shared__ ushort_t sW[128 * 512];  // 128 KB resident B operand

    int t    = threadIdx.x;
    int lane = t & 63;
    int w    = t >> 6;     // wave 0..7
    int lq   = lane >> 4;  // quad
    int lc   = lane & 15;
    int cn0  = blockIdx.x * 128;

    // ---- Phase 0: load + normalize this block's 128 W rows into sW ----
    // wave w: rows w*16 .. w*16+15.
#pragma unroll
    for (int rr = 0; rr < 16; ++rr) {
        int row = w * 16 + rr;
        const float4* p = (const float4*)(W + (size_t)(cn0 + row) * D_N);
        float4 a = p[lane * 2];
        float4 b = p[lane * 2 + 1];
        float ss = a.x*a.x + a.y*a.y + a.z*a.z + a.w*a.w
                 + b.x*b.x + b.y*b.y + b.z*b.z + b.w*b.w;
#pragma unroll
        for (int off = 32; off > 0; off >>= 1) ss += __shfl_xor(ss, off);
        float sc = 1.0f / fmaxf(sqrtf(ss), 1e-12f);
        uint4 o;
        o.x = (unsigned)f2bf(a.x*sc) | ((unsigned)f2bf(a.y*sc) << 16);
        o.y = (unsigned)f2bf(a.z*sc) | ((unsigned)f2bf(a.w*sc) << 16);
        o.z = (unsigned)f2bf(b.x*sc) | ((unsigned)f2bf(b.y*sc) << 16);
        o.w = (unsigned)f2bf(b.z*sc) | ((unsigned)f2bf(b.w*sc) << 16);
        int kc = lane;
        int rs = row ^ (kc & 7);
        *((uint4*)(sW + kc * 1024 + rs * 8)) = o;
    }
    __syncthreads();  // sW ready; only barrier before epilogue

    floatx4 acc[4][8];
#pragma unroll
    for (int i = 0; i < 4; i++)
#pragma unroll
        for (int j = 0; j < 8; j++) acc[i][j] = (floatx4){0.f, 0.f, 0.f, 0.f};

    // A-frag pointers into fragment-linear xnT (16B/lane, 256B contiguous
    // per lq across the 16 lc lanes -> full-line L2 requests).
    const ushort_t* apT[4];
#pragma unroll
    for (int tm = 0; tm < 4; tm++)
        apT[tm] = xnT + ((size_t)lq * 512 + w * 64 + tm * 16 + lc) * 8;

    short8 af[4];
#pragma unroll
    for (int tm = 0; tm < 4; tm++) af[tm] = *(const short8*)(apT[tm]);

    for (int k = 0; k < 16; ++k) {
        short8 afn[4];
        if (k < 15) {
#pragma unroll
            for (int tm = 0; tm < 4; tm++)
                afn[tm] = *(const short8*)(apT[tm] + (k + 1) * 16384);
        }
        int kc = k * 4 + lq;
        short8 bfr[8];
#pragma unroll
        for (int tn = 0; tn < 8; tn++) {
            int rs = (tn * 16 + lc) ^ (kc & 7);
            bfr[tn] = *(const short8*)(sW + kc * 1024 + rs * 8);
        }
#pragma unroll
        for (int tm = 0; tm < 4; tm++)
#pragma unroll
            for (int tn = 0; tn < 8; tn++)
                acc[tm][tn] = __builtin_amdgcn_mfma_f32_16x16x32_bf16(
                    af[tm], bfr[tn], acc[tm][tn], 0, 0, 0);
        if (k < 15) {
#pragma unroll
            for (int tm = 0; tm < 4; tm++) af[tm] = afn[tm];
        }
    }

    // ---- Epilogue. C/D layout: col = lane&15, row = lq*4 + reg. ----
    __syncthreads();                 // all waves done reading sW
    float* rowacc = (float*)sW;      // reuse LDS; each lrow: 1 writer
#pragma unroll
    for (int tm = 0; tm < 4; tm++) {
#pragma unroll
        for (int r = 0; r < 4; r++) {
            int lrow = w * 64 + tm * 16 + lq * 4 + r;  // 0..511, unique
            int yv   = y[lrow];
            float esum = 0.0f;
#pragma unroll
            for (int tn = 0; tn < 8; tn++) {
                int gcol = cn0 + tn * 16 + lc;
                float theta = acc[tm][tn][r];
                if (gcol == yv) {
                    tgt[lrow] = theta;  // exactly one writer device-wide
                } else {
                    esum += __expf(S_SCALE * theta);
                }
            }
#pragma unroll
            for (int off = 1; off < 16; off <<= 1) esum += __shfl_xor(esum, off);
            if (lc == 0) rowacc[lrow] = esum;
        }
    }
    __syncthreads();
    atomicAdd(&rowsumR[(blockIdx.x & (NREP - 1)) * B_N + t], rowacc[t]);
}

__global__ void finalize_kernel(const float* __restrict__ rowsumR,
                                const float* __restrict__ tgt,
                                float* __restrict__ out) {
    __shared__ float red[256];
    int t = threadIdx.x;
    float s = 0.0f;
    for (int r = t; r < B_N; r += 256) {
        float rs = 0.0f;
#pragma unroll
        for (int i = 0; i < NREP; ++i) rs += rowsumR[i * B_N + r];
        float tv = tgt[r];
        tv = fminf(fmaxf(tv, -1.0f + EPS_C), 1.0f - EPS_C);
        float num = S_SCALE * cosf(acosf(tv) + MARGIN);
        float den = expf(num) + rs;
        s += num - logf(den);
    }
    red[t] = s;
    __syncthreads();
    for (int o = 128; o > 0; o >>= 1) {
        if (t < o) red[t] += red[t + o];
        __syncthreads();
    }
    if (t == 0) out[0] = -red[0] / (float)B_N;
}

extern "C" void kernel_launch(void* const* d_in, const int* in_sizes, int n_in,
                              void* d_out, int out_size, void* d_ws, size_t ws_size,
                              hipStream_t stream) {
    const float* x = (const float*)d_in[0];
    const int*   y = (const int*)d_in[1];
    const float* W = (const float*)d_in[2];
    float* out = (float*)d_out;

    char* ws = (char*)d_ws;
    ushort_t* xnT   = (ushort_t*)ws;                    // 512 KB (frag-linear)
    float* rowsumR  = (float*)(ws + 524288);            // 32 KB (16 replicas)
    float* tgt      = rowsumR + NREP * B_N;             // 2 KB

    xprep_kernel<<<129, 256, 0, stream>>>(x, xnT, rowsumR);
    gemm_fused_kernel<<<C_N / 128, 512, 0, stream>>>(W, xnT, y, rowsumR, tgt);
    finalize_kernel<<<1, 256, 0, stream>>>(rowsumR, tgt, out);
}

// Round 7
// 220.815 us; speedup vs baseline: 1.0399x; 1.0399x over previous
//
#include <hip/hip_runtime.h>

// ArcFace loss, MI355X. B=512, D=512, C=64000, s=64, m=0.5.
// R7 = R5 structure (64KB LDS sW, 2 blocks/CU, frag-linear xnT) +
// NONTEMPORAL W loads. Theory: phase-0's 131 MB W stream was thrashing
// xnT (512 KB) out of each XCD L2, turning every K-loop A-frag load into
// a ~600-900 cyc L3/HBM miss (explains the ~3-6k cyc/iter wall). `nt`
// W loads keep xnT L2-resident. Also: register prefetch of next-k af.

#define B_N 512
#define D_N 512
#define C_N 64000
#define S_SCALE 64.0f
#define MARGIN 0.5f
#define EPS_C 1e-7f
#define NREP 16

typedef unsigned short ushort_t;
typedef __attribute__((ext_vector_type(8))) short short8;   // 8 bf16 (4 VGPRs)
typedef __attribute__((ext_vector_type(4))) float floatx4;  // MFMA acc
typedef __attribute__((ext_vector_type(4))) float fvec4;    // for nt loads

__device__ __forceinline__ ushort_t f2bf(float f) {
    unsigned int u = __float_as_uint(f);
    u += 0x7fffu + ((u >> 16) & 1u);  // round-to-nearest-even
    return (ushort_t)(u >> 16);
}

// Normalize x rows -> bf16 in fragment-linear layout:
//   xnT element addr = (kc*512 + row)*8 + j,  kc = k/8 in [0,64), j = k%8.
// Blocks 0..127: 4 rows each. Block 128: zero rowsum replicas.
__global__ void xprep_kernel(const float* __restrict__ x,
                             ushort_t* __restrict__ xnT,
                             float* __restrict__ rowsumR) {
    int b = blockIdx.x;
    int t = threadIdx.x;
    if (b == 128) {
#pragma unroll
        for (int i = 0; i < NREP * B_N / 256; ++i)
            rowsumR[i * 256 + t] = 0.0f;
        return;
    }
    int row  = b * 4 + (t >> 6);
    int lane = t & 63;
    const float4* p = (const float4*)(x + (size_t)row * D_N);
    float4 v0 = p[lane * 2];        // elems [lane*8 .. lane*8+3]
    float4 v1 = p[lane * 2 + 1];    // elems [lane*8+4 .. lane*8+7]
    float ss = v0.x*v0.x + v0.y*v0.y + v0.z*v0.z + v0.w*v0.w
             + v1.x*v1.x + v1.y*v1.y + v1.z*v1.z + v1.w*v1.w;
#pragma unroll
    for (int off = 32; off > 0; off >>= 1) ss += __shfl_xor(ss, off);
    float sc = 1.0f / fmaxf(sqrtf(ss), 1e-12f);
    uint4 o;
    o.x = (unsigned)f2bf(v0.x*sc) | ((unsigned)f2bf(v0.y*sc) << 16);
    o.y = (unsigned)f2bf(v0.z*sc) | ((unsigned)f2bf(v0.w*sc) << 16);
    o.z = (unsigned)f2bf(v1.x*sc) | ((unsigned)f2bf(v1.y*sc) << 16);
    o.w = (unsigned)f2bf(v1.z*sc) | ((unsigned)f2bf(v1.w*sc) << 16);
    *((uint4*)(xnT + ((size_t)(lane << 9) + row) * 8)) = o;
}

// One block = 64 classes x all 512 batch rows. 8 waves; wave w owns rows
// [w*64, w*64+64) x cols [0,64) as 4x4 mfma_f32_16x16x32_bf16 frags.
// sW (XOR swizzle): addr = kc*512 + (row^(kc&7))*8 + k&7, 0 conflicts.
// W loaded NONTEMPORAL (stream-once; don't evict xnT from L2).
__global__ __launch_bounds__(512, 4)
void gemm_fused_kernel(const float* __restrict__ W,
                       const ushort_t* __restrict__ xnT,
                       const int* __restrict__ y,
                       float* __restrict__ rowsumR,
                       float* __restrict__ tgt) {
    __shared__ ushort_t sW[64 * 512];  // 64 KB resident B operand

    int t    = threadIdx.x;
    int lane = t & 63;
    int w    = t >> 6;     // wave 0..7
    int lq   = lane >> 4;  // quad
    int lc   = lane & 15;
    int cn0  = blockIdx.x * 64;

    // ---- Phase 0: load (nt) + normalize this block's 64 W rows ----
#pragma unroll
    for (int rr = 0; rr < 8; ++rr) {
        int row = w * 8 + rr;
        const fvec4* p = (const fvec4*)(W + (size_t)(cn0 + row) * D_N);
        fvec4 a = __builtin_nontemporal_load(p + lane * 2);
        fvec4 b = __builtin_nontemporal_load(p + lane * 2 + 1);
        float ss = a.x*a.x + a.y*a.y + a.z*a.z + a.w*a.w
                 + b.x*b.x + b.y*b.y + b.z*b.z + b.w*b.w;
#pragma unroll
        for (int off = 32; off > 0; off >>= 1) ss += __shfl_xor(ss, off);
        float sc = 1.0f / fmaxf(sqrtf(ss), 1e-12f);
        uint4 o;
        o.x = (unsigned)f2bf(a.x*sc) | ((unsigned)f2bf(a.y*sc) << 16);
        o.y = (unsigned)f2bf(a.z*sc) | ((unsigned)f2bf(a.w*sc) << 16);
        o.z = (unsigned)f2bf(b.x*sc) | ((unsigned)f2bf(b.y*sc) << 16);
        o.w = (unsigned)f2bf(b.z*sc) | ((unsigned)f2bf(b.w*sc) << 16);
        int kc = lane;
        int rs = row ^ (kc & 7);
        *((uint4*)(sW + kc * 512 + rs * 8)) = o;
    }
    __syncthreads();  // sW ready; only barrier before epilogue

    floatx4 acc[4][4];
#pragma unroll
    for (int i = 0; i < 4; i++)
#pragma unroll
        for (int j = 0; j < 4; j++) acc[i][j] = (floatx4){0.f, 0.f, 0.f, 0.f};

    // A-frag pointers into fragment-linear xnT: per lq, the 16 lc lanes
    // read 256 B contiguous (full L2 lines).
    const ushort_t* apT[4];
#pragma unroll
    for (int tm = 0; tm < 4; tm++)
        apT[tm] = xnT + ((size_t)lq * 512 + w * 64 + tm * 16 + lc) * 8;

    short8 af[4];
#pragma unroll
    for (int tm = 0; tm < 4; tm++) af[tm] = *(const short8*)(apT[tm]);

    for (int k = 0; k < 16; ++k) {
        short8 afn[4];
        if (k < 15) {
#pragma unroll
            for (int tm = 0; tm < 4; tm++)
                afn[tm] = *(const short8*)(apT[tm] + (k + 1) * 16384);
        }
        int kc = k * 4 + lq;
        short8 bfr[4];
#pragma unroll
        for (int tn = 0; tn < 4; tn++) {
            int rs = (tn * 16 + lc) ^ (kc & 7);
            bfr[tn] = *(const short8*)(sW + kc * 512 + rs * 8);
        }
#pragma unroll
        for (int tm = 0; tm < 4; tm++)
#pragma unroll
            for (int tn = 0; tn < 4; tn++)
                acc[tm][tn] = __builtin_amdgcn_mfma_f32_16x16x32_bf16(
                    af[tm], bfr[tn], acc[tm][tn], 0, 0, 0);
        if (k < 15) {
#pragma unroll
            for (int tm = 0; tm < 4; tm++) af[tm] = afn[tm];
        }
    }

    // ---- Epilogue. C/D layout: col = lane&15, row = lq*4 + reg. ----
    __syncthreads();                 // all waves done reading sW
    float* rowacc = (float*)sW;      // reuse LDS; each lrow: 1 writer
#pragma unroll
    for (int tm = 0; tm < 4; tm++) {
#pragma unroll
        for (int r = 0; r < 4; r++) {
            int lrow = w * 64 + tm * 16 + lq * 4 + r;  // 0..511, unique
            int yv   = y[lrow];
            float esum = 0.0f;
#pragma unroll
            for (int tn = 0; tn < 4; tn++) {
                int gcol = cn0 + tn * 16 + lc;
                float theta = acc[tm][tn][r];
                if (gcol == yv) {
                    tgt[lrow] = theta;  // exactly one writer device-wide
                } else {
                    esum += __expf(S_SCALE * theta);
                }
            }
#pragma unroll
            for (int off = 1; off < 16; off <<= 1) esum += __shfl_xor(esum, off);
            if (lc == 0) rowacc[lrow] = esum;
        }
    }
    __syncthreads();
    atomicAdd(&rowsumR[(blockIdx.x & (NREP - 1)) * B_N + t], rowacc[t]);
}

__global__ void finalize_kernel(const float* __restrict__ rowsumR,
                                const float* __restrict__ tgt,
                                float* __restrict__ out) {
    __shared__ float red[256];
    int t = threadIdx.x;
    float s = 0.0f;
    for (int r = t; r < B_N; r += 256) {
        float rs = 0.0f;
#pragma unroll
        for (int i = 0; i < NREP; ++i) rs += rowsumR[i * B_N + r];
        float tv = tgt[r];
        tv = fminf(fmaxf(tv, -1.0f + EPS_C), 1.0f - EPS_C);
        float num = S_SCALE * cosf(acosf(tv) + MARGIN);
        float den = expf(num) + rs;
        s += num - logf(den);
    }
    red[t] = s;
    __syncthreads();
    for (int o = 128; o > 0; o >>= 1) {
        if (t < o) red[t] += red[t + o];
        __syncthreads();
    }
    if (t == 0) out[0] = -red[0] / (float)B_N;
}

extern "C" void kernel_launch(void* const* d_in, const int* in_sizes, int n_in,
                              void* d_out, int out_size, void* d_ws, size_t ws_size,
                              hipStream_t stream) {
    const float* x = (const float*)d_in[0];
    const int*   y = (const int*)d_in[1];
    const float* W = (const float*)d_in[2];
    float* out = (float*)d_out;

    char* ws = (char*)d_ws;
    ushort_t* xnT   = (ushort_t*)ws;                    // 512 KB (frag-linear)
    float* rowsumR  = (float*)(ws + 524288);            // 32 KB (16 replicas)
    float* tgt      = rowsumR + NREP * B_N;             // 2 KB

    xprep_kernel<<<129, 256, 0, stream>>>(x, xnT, rowsumR);
    gemm_fused_kernel<<<C_N / 64, 512, 0, stream>>>(W, xnT, y, rowsumR, tgt);
    finalize_kernel<<<1, 256, 0, stream>>>(rowsumR, tgt, out);
}